// Round 8
// baseline (1318.419 us; speedup 1.0000x reference)
//
#include <hip/hip_runtime.h>
#include <hip/hip_fp16.h>
#include <math.h>

// Problem constants
#define NS 4096      // N stocks
#define DIM 512      // D
#define NH 8         // heads
#define HD 64        // head dim
#define M2 4098      // N + 2 nodes
#define MPAD 4224    // m padded to multiple of 32 (264 frags of 16)
#define KKEEP 2048u  // top-k keep

// Output layout (floats): final_out | raw_scores | gate_mean | attn_mean
#define OUT_F 0
#define OUT_R 2097152          // 4096*512
#define OUT_G 18882560         // + 4096*4098
#define OUT_A 18882561

typedef __attribute__((ext_vector_type(8))) short bf16x8;
typedef __attribute__((ext_vector_type(4))) float f32x4;

__device__ __forceinline__ float sigmoidf_(float x) { return 1.0f / (1.0f + __expf(-x)); }

__device__ __forceinline__ unsigned short btrunc(float f) {   // f32 -> bf16 RNE
  unsigned u = __float_as_uint(f);
  u = u + 0x7FFFu + ((u >> 16) & 1u);
  return (unsigned short)(u >> 16);
}
__device__ __forceinline__ float bton(unsigned short h) {
  return __uint_as_float(((unsigned)h) << 16);
}

// wave suffix-scan over 256 bins (4/lane) and rank pick; returns bin + count-strictly-above
__device__ __forceinline__ void scan_pick(unsigned c0, unsigned c1, unsigned c2, unsigned c3,
                                          unsigned k_rem, int lane,
                                          unsigned& bsel_out, unsigned& nxt_out) {
  unsigned run = c0 + c1 + c2 + c3;
  #pragma unroll
  for (int off = 1; off < 64; off <<= 1) {
    unsigned o_ = __shfl_down(run, off, 64);
    if (lane + off < 64) run += o_;
  }
  unsigned s0 = run, s1 = run - c0, s2 = s1 - c1, s3 = s2 - c2, s4 = s3 - c3;
  int which = -1;
  if      (s0 >= k_rem && s1 < k_rem) which = 0;
  else if (s1 >= k_rem && s2 < k_rem) which = 1;
  else if (s2 >= k_rem && s3 < k_rem) which = 2;
  else if (s3 >= k_rem && s4 < k_rem) which = 3;
  unsigned long long bal = __ballot(which >= 0);
  int src = (int)__ffsll(bal) - 1;
  unsigned nxtv = (which == 0) ? s1 : (which == 1) ? s2 : (which == 2) ? s3 : s4;
  unsigned bsel = (unsigned)(4 * lane + (which < 0 ? 0 : which));
  bsel_out = (unsigned)__shfl((int)bsel, src, 64);
  nxt_out  = (unsigned)__shfl((int)nxtv, src, 64);
}

// ---------------- regime_mod = sigmoid([zp,zs] @ Wg.T + bg) ----------------
__global__ __launch_bounds__(256) void regime_kernel(
    const float* __restrict__ zp, const float* __restrict__ zs,
    const float* __restrict__ Wg, const float* __restrict__ bg,
    float* __restrict__ regime) {
  __shared__ float zc[1024];
  int t = threadIdx.x;
  for (int i = t; i < 512; i += 256) { zc[i] = zp[i]; zc[512 + i] = zs[i]; }
  __syncthreads();
  for (int j = t; j < 512; j += 256) {
    const float4* w = (const float4*)(Wg + (size_t)j * 1024);
    float acc = 0.f;
    #pragma unroll 8
    for (int i = 0; i < 256; i++) {
      float4 wv = w[i];
      acc += wv.x * zc[4*i] + wv.y * zc[4*i+1] + wv.z * zc[4*i+2] + wv.w * zc[4*i+3];
    }
    regime[j] = sigmoidf_(acc + bg[j]);
  }
}

// ---------------- generic f32 -> bf16 convert ----------------
__global__ __launch_bounds__(256) void conv_bf(
    const float* __restrict__ src, unsigned short* __restrict__ dst, int n4) {
  int i4 = blockIdx.x * 256 + threadIdx.x;
  if (i4 >= n4) return;
  float4 v = *(const float4*)(src + (size_t)i4 * 4);
  ushort4 o; o.x = btrunc(v.x); o.y = btrunc(v.y); o.z = btrunc(v.z); o.w = btrunc(v.w);
  *(ushort4*)(dst + (size_t)i4 * 4) = o;
}

// ---------------- nodes = concat(zp, zs, sf) in bf16 ----------------
__global__ __launch_bounds__(256) void build_nodes_bf(
    const float* __restrict__ zp, const float* __restrict__ zs,
    const float* __restrict__ sf, unsigned short* __restrict__ nb) {
  int i4 = blockIdx.x * 256 + threadIdx.x;
  if (i4 >= (M2 * DIM) / 4) return;
  int idx = i4 * 4;
  int m = idx >> 9, c = idx & 511;
  const float* src = (m == 0) ? (zp + c) : (m == 1) ? (zs + c)
                               : (sf + (size_t)(m - 2) * 512 + c);
  float4 v = *(const float4*)src;
  ushort4 o; o.x = btrunc(v.x); o.y = btrunc(v.y); o.z = btrunc(v.z); o.w = btrunc(v.w);
  *(ushort4*)(nb + idx) = o;
}

// ---------------- bf16 MFMA GEMM: C = (A[M][K] @ B[N][K]^T * scale + bias) * cscale ----------------
// 128x128 tile, 256 threads (4 waves in 2x2), BK=32.
// mode 0: C fp32 [M][ldc]; mode 1: C bf16 [M][ldc]; mode 2: C bf16 transposed [N][ldc] (C[col][row]).
#define LSTR 40
__global__ __launch_bounds__(256) void gemm_bf16(
    const unsigned short* __restrict__ A, const unsigned short* __restrict__ B,
    const float* __restrict__ bias, const float* __restrict__ cscale,
    float* __restrict__ Cf, unsigned short* __restrict__ Cb,
    int M, int N, int K, int lda, int ldb, int ldc, float scale, int mode) {
  __shared__ unsigned short As[128 * LSTR];
  __shared__ unsigned short Bs[128 * LSTR];
  const int t = threadIdx.x;
  const int w = t >> 6, lane = t & 63;
  const int wr = w >> 1, wc = w & 1;
  const int lr = lane & 15, lg = lane >> 4;
  const int bm = blockIdx.y * 128, bn = blockIdx.x * 128;
  f32x4 acc[4][4] = {};
  for (int k0 = 0; k0 < K; k0 += 32) {
    #pragma unroll
    for (int i = 0; i < 2; i++) {
      int q = t + i * 256;
      int row = q >> 2;
      int ko = (q & 3) * 8;
      bf16x8 av = {};
      int gr = bm + row;
      if (gr < M) av = *(const bf16x8*)(A + (size_t)gr * lda + k0 + ko);
      *(bf16x8*)(As + row * LSTR + ko) = av;
      bf16x8 bv = {};
      int gbr = bn + row;
      if (gbr < N) bv = *(const bf16x8*)(B + (size_t)gbr * ldb + k0 + ko);
      *(bf16x8*)(Bs + row * LSTR + ko) = bv;
    }
    __syncthreads();
    {
      bf16x8 af[4], bfr[4];
      #pragma unroll
      for (int i = 0; i < 4; i++)
        af[i] = *(const bf16x8*)(As + (64 * wr + 16 * i + lr) * LSTR + lg * 8);
      #pragma unroll
      for (int j = 0; j < 4; j++)
        bfr[j] = *(const bf16x8*)(Bs + (64 * wc + 16 * j + lr) * LSTR + lg * 8);
      #pragma unroll
      for (int i = 0; i < 4; i++)
        #pragma unroll
        for (int j = 0; j < 4; j++)
          acc[i][j] = __builtin_amdgcn_mfma_f32_16x16x32_bf16(af[i], bfr[j], acc[i][j], 0, 0, 0);
    }
    __syncthreads();
  }
  // epilogue
  #pragma unroll
  for (int i = 0; i < 4; i++) {
    #pragma unroll
    for (int j = 0; j < 4; j++) {
      #pragma unroll
      for (int q = 0; q < 4; q++) {
        int row = bm + 64 * wr + 16 * i + lg * 4 + q;
        int col = bn + 64 * wc + 16 * j + lr;
        if (row < M && col < N) {
          float v = acc[i][j][q] * scale;
          if (bias)   v += bias[col];
          if (cscale) v *= cscale[col];
          if (mode == 0)      Cf[(size_t)row * ldc + col] = v;
          else if (mode == 1) Cb[(size_t)row * ldc + col] = btrunc(v);
          else                Cb[(size_t)col * ldc + row] = btrunc(v);
        }
      }
    }
  }
}

// ---------------- fused attention ----------------
// 256 blocks (one 16-row tile each, 1/CU), 1024 threads = 16 waves, loop h=0..7.
// ph1: QK^T MFMA; per-element key -> S write + FUSED high-byte histogram atomic +
//      running per-row max in VGPRs (published via atomicMax).
// ph2 (2 sweeps only): suffix-scan prebuilt hist -> boundary bin; pass-1 sweep
//      (compare + boundary-bin atomics) -> exact threshold; exp sweep with
//      precomputed lmax -> unnormalized e to LDS, invZ in reg.
// attn_mean accumulated in 34 packed-f16 VGPRs; PV MFMA K-split; LDS reduce.
#define SROWB 8464                    // 8448 data + 16 pad (odd 16B units -> bank spread)
#define QOFF  (16 * SROWB)            // 135424
#define HOFF  (QOFF + 16 * 72 * 2)    // + 2304 = 137728
#define MKOFF (HOFF + 16 * 256 * 4)   // + 16384 = 154112
#define SMEMSZ (MKOFF + 64)           // 154176

__global__ __launch_bounds__(1024, 4) void fused_attn(
    const unsigned short* __restrict__ Qbf, const unsigned short* __restrict__ Kbf,
    const unsigned short* __restrict__ Vt, unsigned short* __restrict__ aobf,
    float* __restrict__ attn_mean_out) {
  extern __shared__ char dsm[];
  unsigned short* qt = (unsigned short*)(dsm + QOFF);
  unsigned* hist = (unsigned*)(dsm + HOFF);    // [16 rows][256]
  unsigned* maxk = (unsigned*)(dsm + MKOFF);   // [16 rows]

  const int n0 = blockIdx.x * 16;
  const int t = threadIdx.x;
  const int w = t >> 6, lane = t & 63;
  const int lr = lane & 15, lg = lane >> 4;
  unsigned* hw = hist + w * 256;
  const int r = w;                              // row owned by this wave
  const unsigned swz = (unsigned)((r & 7) << 4);

  __half2 am2[34];
  const __half2 zero2 = __floats2half2_rn(0.f, 0.f);
  #pragma unroll
  for (int j = 0; j < 34; ++j) am2[j] = zero2;

  for (int h = 0; h < NH; ++h) {
    // ---- ph0: Q tile -> LDS; zero this wave's hist + row max ----
    qt[(t >> 6) * 72 + (t & 63)] = Qbf[(size_t)(n0 + (t >> 6)) * DIM + h * HD + (t & 63)];
    hw[lane] = 0u; hw[lane + 64] = 0u; hw[lane + 128] = 0u; hw[lane + 192] = 0u;
    if (lane == 0) maxk[w] = 0u;
    __syncthreads();

    // ---- ph1: S = Q @ K^T * 0.125 -> LDS bf16 (swizzled) + fused hist/max ----
    {
      bf16x8 a0 = *(const bf16x8*)(qt + lr * 72 + lg * 8);
      bf16x8 a1 = *(const bf16x8*)(qt + lr * 72 + 32 + lg * 8);
      unsigned pmax[4] = {0u, 0u, 0u, 0u};
      #pragma unroll
      for (int f = 0; f < 17; ++f) {
        if (f < 16 || w < 8) {                 // fi < 264
          int m0 = (w + 16 * f) * 16;
          const unsigned short* kp = Kbf + (size_t)(m0 + lr) * DIM + h * HD + lg * 8;
          bf16x8 b0 = *(const bf16x8*)(kp);
          bf16x8 b1 = *(const bf16x8*)(kp + 32);
          f32x4 c = {0.f, 0.f, 0.f, 0.f};
          c = __builtin_amdgcn_mfma_f32_16x16x32_bf16(a0, b0, c, 0, 0, 0);
          c = __builtin_amdgcn_mfma_f32_16x16x32_bf16(a1, b1, c, 0, 0, 0);
          int m = m0 + lr;
          bool inm = (m < M2);
          bool sel = inm && (m >= 2);
          #pragma unroll
          for (int q = 0; q < 4; ++q) {
            int rr = lg * 4 + q;
            unsigned short us = btrunc(c[q] * 0.125f);
            *(unsigned short*)(dsm + rr * SROWB + ((2 * m) ^ ((rr & 7) << 4))) = us;
            unsigned key = (unsigned)us ^ ((us & 0x8000u) ? 0xFFFFu : 0x8000u);
            if (inm && key > pmax[q]) pmax[q] = key;
            if (sel) atomicAdd(&hist[rr * 256 + (key >> 8)], 1u);
          }
        }
      }
      #pragma unroll
      for (int q = 0; q < 4; ++q) atomicMax(&maxk[lg * 4 + q], pmax[q]);
    }
    __syncthreads();

    // ---- ph2: 2-sweep select + exp for row r = w; invZ stays in reg ----
    float invZ;
    {
      unsigned mk = maxk[r];
      float lmax = bton((unsigned short)(mk ^ ((mk & 0x8000u) ? 0x8000u : 0xFFFFu)));

      // pass 0: from prebuilt histogram (no sweep)
      unsigned tb, k_rem = KKEEP;
      {
        unsigned c0 = hw[4*lane], c1 = hw[4*lane+1], c2 = hw[4*lane+2], c3 = hw[4*lane+3];
        unsigned nxtv;
        scan_pick(c0, c1, c2, c3, k_rem, lane, tb, nxtv);
        k_rem -= nxtv;
      }

      // zero bins for low-byte pass (wave-private)
      hw[lane] = 0u; hw[lane + 64] = 0u; hw[lane + 128] = 0u; hw[lane + 192] = 0u;

      // pass 1 sweep: compare-only except boundary-bin atomics
      #pragma unroll
      for (int c = 0; c < 9; ++c) {
        if (c < 8 || lane < 16) {
          uint4 pk4 = *(const uint4*)(dsm + r * SROWB + (((unsigned)(c * 1024 + lane * 16)) ^ swz));
          const unsigned* pw = (const unsigned*)&pk4;
          #pragma unroll
          for (int p2 = 0; p2 < 4; ++p2) {
            unsigned pk = pw[p2];
            int mb = c * 512 + lane * 8 + p2 * 2;
            #pragma unroll
            for (int e = 0; e < 2; ++e) {
              int m = mb + e;
              unsigned u = (e == 0) ? (pk & 0xFFFFu) : (pk >> 16);
              unsigned key = u ^ ((u & 0x8000u) ? 0xFFFFu : 0x8000u);
              if (m >= 2 && m < M2 && (key >> 8) == tb) atomicAdd(&hw[key & 255u], 1u);
            }
          }
        }
      }
      unsigned thrkey;
      {
        unsigned c0 = hw[4*lane], c1 = hw[4*lane+1], c2 = hw[4*lane+2], c3 = hw[4*lane+3];
        unsigned bsel, nxtv;
        scan_pick(c0, c1, c2, c3, k_rem, lane, bsel, nxtv);
        thrkey = (tb << 8) | bsel;
      }

      // exp sweep (kept only) + sum; stream unnormalized e (bf16) back to LDS
      float lsum = 0.f;
      #pragma unroll
      for (int c = 0; c < 9; ++c) {
        if (c < 8 || lane < 16) {
          char* ap = dsm + r * SROWB + (((unsigned)(c * 1024 + lane * 16)) ^ swz);
          uint4 pk4 = *(const uint4*)ap;
          unsigned* pw = (unsigned*)&pk4;
          #pragma unroll
          for (int p2 = 0; p2 < 4; ++p2) {
            unsigned pk = pw[p2];
            int mb = c * 512 + lane * 8 + p2 * 2;
            unsigned outw = 0;
            #pragma unroll
            for (int e = 0; e < 2; ++e) {
              int m = mb + e;
              unsigned u = (e == 0) ? (pk & 0xFFFFu) : (pk >> 16);
              unsigned key = u ^ ((u & 0x8000u) ? 0xFFFFu : 0x8000u);
              bool kept = (m < 2) || (m < M2 && key >= thrkey);
              float evf = kept ? __expf(bton((unsigned short)u) - lmax) : 0.f;
              unsigned short eb = btrunc(evf);
              lsum += bton(eb);
              outw |= ((unsigned)eb) << (16 * e);
            }
            pw[p2] = outw;
          }
          *(uint4*)ap = pk4;
        }
      }
      #pragma unroll
      for (int off = 32; off > 0; off >>= 1) lsum += __shfl_xor(lsum, off, 64);
      invZ = 1.0f / lsum;
    }

    // ---- ph2.5: attn_mean accumulation in packed f16 (own row) ----
    #pragma unroll
    for (int jj = 0; jj < 17; ++jj) {
      if (jj < 16 || lane < 32) {
        int c = jj * 64 + lane;                          // 4-elem chunk, m = 4c..4c+3
        uint2 w2 = *(const uint2*)(dsm + r * SROWB + (((unsigned)(8 * c)) ^ swz));
        float e0 = bton((unsigned short)(w2.x & 0xFFFFu)) * invZ;
        float e1 = bton((unsigned short)(w2.x >> 16)) * invZ;
        float e2 = bton((unsigned short)(w2.y & 0xFFFFu)) * invZ;
        float e3 = bton((unsigned short)(w2.y >> 16)) * invZ;
        am2[2*jj]   = __hadd2(am2[2*jj],   __floats2half2_rn(e0, e1));
        am2[2*jj+1] = __hadd2(am2[2*jj+1], __floats2half2_rn(e2, e3));
      }
    }
    __syncthreads();   // all waves' e finalized before PV reads all rows

    // ---- ph3: PV = e @ V (K-split, slice s = w + 16*ks); scale by invZ in epilogue ----
    {
      f32x4 o0 = {0.f,0.f,0.f,0.f}, o1 = o0, o2 = o0, o3 = o0;
      const unsigned short* Vb = Vt + (size_t)(h * HD) * MPAD;
      #pragma unroll
      for (int ks = 0; ks < 9; ++ks) {
        if (ks < 8 || w < 4) {                 // slice < 132
          int kk = (w + 16 * ks) * 32 + lg * 8;
          bf16x8 a = *(const bf16x8*)(dsm + lr * SROWB + ((2 * kk) ^ ((lr & 7) << 4)));
          bf16x8 b0 = *(const bf16x8*)(Vb + (size_t)(lr) * MPAD + kk);
          bf16x8 b1 = *(const bf16x8*)(Vb + (size_t)(16 + lr) * MPAD + kk);
          bf16x8 b2 = *(const bf16x8*)(Vb + (size_t)(32 + lr) * MPAD + kk);
          bf16x8 b3 = *(const bf16x8*)(Vb + (size_t)(48 + lr) * MPAD + kk);
          o0 = __builtin_amdgcn_mfma_f32_16x16x32_bf16(a, b0, o0, 0, 0, 0);
          o1 = __builtin_amdgcn_mfma_f32_16x16x32_bf16(a, b1, o1, 0, 0, 0);
          o2 = __builtin_amdgcn_mfma_f32_16x16x32_bf16(a, b2, o2, 0, 0, 0);
          o3 = __builtin_amdgcn_mfma_f32_16x16x32_bf16(a, b3, o3, 0, 0, 0);
        }
      }
      __syncthreads();   // all waves done reading e
      float* part = (float*)dsm;   // [16][16][64] = 64 KB, overlays S rows
      #pragma unroll
      for (int q = 0; q < 4; q++) {
        int row = lg * 4 + q;
        part[w * 1024 + row * 64 +      lr] = o0[q];
        part[w * 1024 + row * 64 + 16 + lr] = o1[q];
        part[w * 1024 + row * 64 + 32 + lr] = o2[q];
        part[w * 1024 + row * 64 + 48 + lr] = o3[q];
      }
      __syncthreads();
      {
        float s = 0.f;
        #pragma unroll
        for (int ww = 0; ww < 16; ++ww) s += part[ww * 1024 + t];
        aobf[(size_t)(n0 + (t >> 6)) * DIM + h * HD + (t & 63)] = btrunc(s * invZ);
      }
      // next head's post-ph0 barrier protects part reads from S overwrite
    }
  }

  // ---- write attn_mean once (row r = w; chunk c = jj*64+lane -> floats 4c..4c+3) ----
  {
    float* dst = attn_mean_out + (size_t)(n0 + r) * M2;
    #pragma unroll
    for (int jj = 0; jj < 17; ++jj) {
      if (jj < 16) {
        int c = jj * 64 + lane;
        float2 lo, hi;
        lo.x = __low2float(am2[2*jj])  * 0.125f;
        lo.y = __high2float(am2[2*jj]) * 0.125f;
        hi.x = __low2float(am2[2*jj+1])  * 0.125f;
        hi.y = __high2float(am2[2*jj+1]) * 0.125f;
        *(float2*)(dst + 4 * c)     = lo;
        *(float2*)(dst + 4 * c + 2) = hi;
      } else if (lane == 0) {                  // m 4096, 4097
        dst[4096] = __low2float(am2[32])  * 0.125f;
        dst[4097] = __high2float(am2[32]) * 0.125f;
      }
    }
  }
}

// ---------------- concat(sfbf, bf16(pj)) ----------------
__global__ __launch_bounds__(256) void cat_bf(
    const unsigned short* __restrict__ sfbf, const float* __restrict__ pj,
    unsigned short* __restrict__ cat) {
  int i4 = blockIdx.x * 256 + threadIdx.x;
  if (i4 >= (4096 * 1024) / 4) return;
  int idx = i4 * 4;
  int n = idx >> 10, c = idx & 1023;
  if (c < 512) {
    *(ushort4*)(cat + idx) = *(const ushort4*)(sfbf + (size_t)n * 512 + c);
  } else {
    float4 v = *(const float4*)(pj + (size_t)n * 512 + (c - 512));
    ushort4 o; o.x = btrunc(v.x); o.y = btrunc(v.y); o.z = btrunc(v.z); o.w = btrunc(v.w);
    *(ushort4*)(cat + idx) = o;
  }
}

// ---------------- gate, residual, RMSNorm, gate partial sums ----------------
__global__ __launch_bounds__(256) void final_kernel(
    const float* __restrict__ sf, const float* __restrict__ pj,
    const float* __restrict__ gl, const float* __restrict__ norm_w,
    float* __restrict__ outf, float* __restrict__ gpart) {
  int n = blockIdx.x, t = threadIdx.x;
  __shared__ float red[256];
  size_t base = (size_t)n * 512;
  float g0 = sigmoidf_(gl[base + t]);
  float g1 = sigmoidf_(gl[base + 256 + t]);
  float x0 = sf[base + t], x1 = sf[base + 256 + t];
  float p0 = pj[base + t], p1 = pj[base + 256 + t];
  float gr0 = x0 + g0 * p0, gr1 = x1 + g1 * p1;

  red[t] = g0 + g1;
  __syncthreads();
  for (int off = 128; off > 0; off >>= 1) {
    if (t < off) red[t] += red[t + off];
    __syncthreads();
  }
  if (t == 0) gpart[n] = red[0];
  __syncthreads();

  red[t] = gr0 * gr0 + gr1 * gr1;
  __syncthreads();
  for (int off = 128; off > 0; off >>= 1) {
    if (t < off) red[t] += red[t + off];
    __syncthreads();
  }
  float rms = rsqrtf(red[0] * (1.0f / 512.0f) + 1e-6f);
  outf[base + t] = gr0 * rms * norm_w[t];
  outf[base + 256 + t] = gr1 * rms * norm_w[256 + t];
}

__global__ __launch_bounds__(256) void gate_reduce(
    const float* __restrict__ gpart, float* __restrict__ out_scalar) {
  __shared__ float red[256];
  int t = threadIdx.x;
  float s = 0.f;
  for (int i = t; i < 4096; i += 256) s += gpart[i];
  red[t] = s;
  __syncthreads();
  for (int off = 128; off > 0; off >>= 1) {
    if (t < off) red[t] += red[t + off];
    __syncthreads();
  }
  if (t == 0) out_scalar[0] = red[0] * (1.0f / (4096.0f * 512.0f));
}

extern "C" void kernel_launch(void* const* d_in, const int* in_sizes, int n_in,
                              void* d_out, int out_size, void* d_ws, size_t ws_size,
                              hipStream_t stream) {
  const float* sf  = (const float*)d_in[0];
  const float* zp  = (const float*)d_in[1];
  const float* zs  = (const float*)d_in[2];
  const float* Wq  = (const float*)d_in[3];
  const float* Wk  = (const float*)d_in[4];
  const float* Wv  = (const float*)d_in[5];
  const float* Wg  = (const float*)d_in[6];
  const float* bg  = (const float*)d_in[7];
  const float* Wag = (const float*)d_in[8];
  const float* bag = (const float*)d_in[9];
  const float* nw  = (const float*)d_in[10];
  const float* Wo  = (const float*)d_in[11];
  const float* bo  = (const float*)d_in[12];

  float* out  = (float*)d_out;
  float* outF = out + OUT_F;
  float* outR = out + OUT_R;
  float* outG = out + OUT_G;
  float* outA = out + OUT_A;

  // workspace layout (bytes)
  char* W = (char*)d_ws;
  float*          regime  = (float*)(W + 0);                 // 2048
  float*          gpart   = (float*)(W + 2048);              // 16384
  unsigned short* sfbf    = (unsigned short*)(W + 18432);    // 4,194,304
  unsigned short* nodesbf = (unsigned short*)(W + 4212736);  // 4,196,352
  unsigned short* Qbf     = (unsigned short*)(W + 8409088);  // 4,194,304
  unsigned short* Kbf     = (unsigned short*)(W + 12603392); // 4,325,376 (4224 rows)
  unsigned short* Vt      = (unsigned short*)(W + 16928768); // 4,325,376 (512 x 4224)
  unsigned short* aobf    = (unsigned short*)(W + 21254144); // 4,194,304
  unsigned short* catbf   = (unsigned short*)(W + 25448448); // 8,388,608
  unsigned short* Wqbf    = (unsigned short*)(W + 33837056); // 524,288
  unsigned short* Wkbf    = (unsigned short*)(W + 34361344); // 524,288
  unsigned short* Wvbf    = (unsigned short*)(W + 34885632); // 524,288
  unsigned short* Wobf    = (unsigned short*)(W + 35409920); // 524,288
  unsigned short* Wagbf   = (unsigned short*)(W + 35934208); // 1,048,576
  float*          pj      = (float*)(W + 36982784);          // 8,388,608 -> 45,371,392
  float*          gl      = (float*)(W + 4212736);           // alias over nodesbf+Qbf (dead by then)

  hipFuncSetAttribute((const void*)fused_attn,
                      hipFuncAttributeMaxDynamicSharedMemorySize, SMEMSZ);

  // --- small prep ---
  regime_kernel<<<1, 256, 0, stream>>>(zp, zs, Wg, bg, regime);
  conv_bf<<<2048, 256, 0, stream>>>(sf, sfbf, 524288);
  build_nodes_bf<<<2049, 256, 0, stream>>>(zp, zs, sf, nodesbf);
  conv_bf<<<256, 256, 0, stream>>>(Wq, Wqbf, 65536);
  conv_bf<<<256, 256, 0, stream>>>(Wk, Wkbf, 65536);
  conv_bf<<<256, 256, 0, stream>>>(Wv, Wvbf, 65536);
  conv_bf<<<256, 256, 0, stream>>>(Wo, Wobf, 65536);
  conv_bf<<<512, 256, 0, stream>>>(Wag, Wagbf, 131072);
  hipMemsetAsync(Kbf, 0, 4325376, stream);
  hipMemsetAsync(Vt, 0, 4325376, stream);

  // --- projections (bf16 MFMA) ---
  gemm_bf16<<<dim3(4, 32), 256, 0, stream>>>(sfbf, Wqbf, nullptr, regime, nullptr, Qbf,
                                             4096, 512, 512, 512, 512, 512, 1.0f, 1);
  gemm_bf16<<<dim3(4, 33), 256, 0, stream>>>(nodesbf, Wkbf, nullptr, nullptr, nullptr, Kbf,
                                             M2, 512, 512, 512, 512, 512, 1.0f, 1);
  gemm_bf16<<<dim3(4, 33), 256, 0, stream>>>(nodesbf, Wvbf, nullptr, nullptr, nullptr, Vt,
                                             M2, 512, 512, 512, 512, MPAD, 1.0f, 2);

  // --- raw_scores = (Q @ K^T) * (0.125/8) over full 512 dims ---
  gemm_bf16<<<dim3(33, 32), 256, 0, stream>>>(Qbf, Kbf, nullptr, nullptr, outR, nullptr,
                                              4096, M2, 512, 512, 512, M2, 0.015625f, 0);

  // --- fused attention (256 blocks, 1024 threads, no atomics to global) ---
  fused_attn<<<256, 1024, SMEMSZ, stream>>>(Qbf, Kbf, Vt, aobf, outA);

  // --- output projection + gate + final ---
  gemm_bf16<<<dim3(4, 32), 256, 0, stream>>>(aobf, Wobf, bo, nullptr, pj, nullptr,
                                             4096, 512, 512, 512, 512, 512, 1.0f, 0);
  cat_bf<<<4096, 256, 0, stream>>>(sfbf, pj, catbf);
  gemm_bf16<<<dim3(4, 32), 256, 0, stream>>>(catbf, Wagbf, bag, nullptr, gl, nullptr,
                                             4096, 512, 1024, 1024, 1024, 512, 1.0f, 0);
  final_kernel<<<4096, 256, 0, stream>>>(sf, pj, gl, nw, outF, gpart);
  gate_reduce<<<1, 256, 0, stream>>>(gpart, outG);
}

// Round 9
// 1096.808 us; speedup vs baseline: 1.2021x; 1.2021x over previous
//
#include <hip/hip_runtime.h>
#include <hip/hip_fp16.h>
#include <math.h>

// Problem constants
#define NS 4096      // N stocks
#define DIM 512      // D
#define NH 8         // heads
#define HD 64        // head dim
#define M2 4098      // N + 2 nodes
#define MPAD 4224    // m padded to multiple of 32 (264 frags of 16)
#define KKEEP 2048u  // top-k keep

// Output layout (floats): final_out | raw_scores | gate_mean | attn_mean
#define OUT_F 0
#define OUT_R 2097152          // 4096*512
#define OUT_G 18882560         // + 4096*4098
#define OUT_A 18882561

typedef __attribute__((ext_vector_type(8))) short bf16x8;
typedef __attribute__((ext_vector_type(4))) float f32x4;

__device__ __forceinline__ float sigmoidf_(float x) { return 1.0f / (1.0f + __expf(-x)); }

__device__ __forceinline__ unsigned short btrunc(float f) {   // f32 -> bf16 RNE
  unsigned u = __float_as_uint(f);
  u = u + 0x7FFFu + ((u >> 16) & 1u);
  return (unsigned short)(u >> 16);
}
__device__ __forceinline__ float bton(unsigned short h) {
  return __uint_as_float(((unsigned)h) << 16);
}

// wave suffix-scan over 256 bins (4/lane) and rank pick; returns bin + count-strictly-above
__device__ __forceinline__ void scan_pick(unsigned c0, unsigned c1, unsigned c2, unsigned c3,
                                          unsigned k_rem, int lane,
                                          unsigned& bsel_out, unsigned& nxt_out) {
  unsigned run = c0 + c1 + c2 + c3;
  #pragma unroll
  for (int off = 1; off < 64; off <<= 1) {
    unsigned o_ = __shfl_down(run, off, 64);
    if (lane + off < 64) run += o_;
  }
  unsigned s0 = run, s1 = run - c0, s2 = s1 - c1, s3 = s2 - c2, s4 = s3 - c3;
  int which = -1;
  if      (s0 >= k_rem && s1 < k_rem) which = 0;
  else if (s1 >= k_rem && s2 < k_rem) which = 1;
  else if (s2 >= k_rem && s3 < k_rem) which = 2;
  else if (s3 >= k_rem && s4 < k_rem) which = 3;
  unsigned long long bal = __ballot(which >= 0);
  int src = (int)__ffsll(bal) - 1;
  unsigned nxtv = (which == 0) ? s1 : (which == 1) ? s2 : (which == 2) ? s3 : s4;
  unsigned bsel = (unsigned)(4 * lane + (which < 0 ? 0 : which));
  bsel_out = (unsigned)__shfl((int)bsel, src, 64);
  nxt_out  = (unsigned)__shfl((int)nxtv, src, 64);
}

// ---------------- regime_mod = sigmoid([zp,zs] @ Wg.T + bg) ----------------
__global__ __launch_bounds__(256) void regime_kernel(
    const float* __restrict__ zp, const float* __restrict__ zs,
    const float* __restrict__ Wg, const float* __restrict__ bg,
    float* __restrict__ regime) {
  __shared__ float zc[1024];
  int t = threadIdx.x;
  for (int i = t; i < 512; i += 256) { zc[i] = zp[i]; zc[512 + i] = zs[i]; }
  __syncthreads();
  for (int j = t; j < 512; j += 256) {
    const float4* w = (const float4*)(Wg + (size_t)j * 1024);
    float acc = 0.f;
    #pragma unroll 8
    for (int i = 0; i < 256; i++) {
      float4 wv = w[i];
      acc += wv.x * zc[4*i] + wv.y * zc[4*i+1] + wv.z * zc[4*i+2] + wv.w * zc[4*i+3];
    }
    regime[j] = sigmoidf_(acc + bg[j]);
  }
}

// ---------------- generic f32 -> bf16 convert ----------------
__global__ __launch_bounds__(256) void conv_bf(
    const float* __restrict__ src, unsigned short* __restrict__ dst, int n4) {
  int i4 = blockIdx.x * 256 + threadIdx.x;
  if (i4 >= n4) return;
  float4 v = *(const float4*)(src + (size_t)i4 * 4);
  ushort4 o; o.x = btrunc(v.x); o.y = btrunc(v.y); o.z = btrunc(v.z); o.w = btrunc(v.w);
  *(ushort4*)(dst + (size_t)i4 * 4) = o;
}

// ---------------- nodes = concat(zp, zs, sf) in bf16 ----------------
__global__ __launch_bounds__(256) void build_nodes_bf(
    const float* __restrict__ zp, const float* __restrict__ zs,
    const float* __restrict__ sf, unsigned short* __restrict__ nb) {
  int i4 = blockIdx.x * 256 + threadIdx.x;
  if (i4 >= (M2 * DIM) / 4) return;
  int idx = i4 * 4;
  int m = idx >> 9, c = idx & 511;
  const float* src = (m == 0) ? (zp + c) : (m == 1) ? (zs + c)
                               : (sf + (size_t)(m - 2) * 512 + c);
  float4 v = *(const float4*)src;
  ushort4 o; o.x = btrunc(v.x); o.y = btrunc(v.y); o.z = btrunc(v.z); o.w = btrunc(v.w);
  *(ushort4*)(nb + idx) = o;
}

// ---------------- bf16 MFMA GEMM: C = (A[M][K] @ B[N][K]^T * scale + bias) * cscale ----------------
// 128x128 tile, 256 threads (4 waves in 2x2), BK=32.
// mode 0: C fp32 [M][ldc]; mode 1: C bf16 [M][ldc]; mode 2: C bf16 transposed [N][ldc] (C[col][row]).
#define LSTR 40
__global__ __launch_bounds__(256) void gemm_bf16(
    const unsigned short* __restrict__ A, const unsigned short* __restrict__ B,
    const float* __restrict__ bias, const float* __restrict__ cscale,
    float* __restrict__ Cf, unsigned short* __restrict__ Cb,
    int M, int N, int K, int lda, int ldb, int ldc, float scale, int mode) {
  __shared__ unsigned short As[128 * LSTR];
  __shared__ unsigned short Bs[128 * LSTR];
  const int t = threadIdx.x;
  const int w = t >> 6, lane = t & 63;
  const int wr = w >> 1, wc = w & 1;
  const int lr = lane & 15, lg = lane >> 4;
  const int bm = blockIdx.y * 128, bn = blockIdx.x * 128;
  f32x4 acc[4][4] = {};
  for (int k0 = 0; k0 < K; k0 += 32) {
    #pragma unroll
    for (int i = 0; i < 2; i++) {
      int q = t + i * 256;
      int row = q >> 2;
      int ko = (q & 3) * 8;
      bf16x8 av = {};
      int gr = bm + row;
      if (gr < M) av = *(const bf16x8*)(A + (size_t)gr * lda + k0 + ko);
      *(bf16x8*)(As + row * LSTR + ko) = av;
      bf16x8 bv = {};
      int gbr = bn + row;
      if (gbr < N) bv = *(const bf16x8*)(B + (size_t)gbr * ldb + k0 + ko);
      *(bf16x8*)(Bs + row * LSTR + ko) = bv;
    }
    __syncthreads();
    {
      bf16x8 af[4], bfr[4];
      #pragma unroll
      for (int i = 0; i < 4; i++)
        af[i] = *(const bf16x8*)(As + (64 * wr + 16 * i + lr) * LSTR + lg * 8);
      #pragma unroll
      for (int j = 0; j < 4; j++)
        bfr[j] = *(const bf16x8*)(Bs + (64 * wc + 16 * j + lr) * LSTR + lg * 8);
      #pragma unroll
      for (int i = 0; i < 4; i++)
        #pragma unroll
        for (int j = 0; j < 4; j++)
          acc[i][j] = __builtin_amdgcn_mfma_f32_16x16x32_bf16(af[i], bfr[j], acc[i][j], 0, 0, 0);
    }
    __syncthreads();
  }
  // epilogue
  #pragma unroll
  for (int i = 0; i < 4; i++) {
    #pragma unroll
    for (int j = 0; j < 4; j++) {
      #pragma unroll
      for (int q = 0; q < 4; q++) {
        int row = bm + 64 * wr + 16 * i + lg * 4 + q;
        int col = bn + 64 * wc + 16 * j + lr;
        if (row < M && col < N) {
          float v = acc[i][j][q] * scale;
          if (bias)   v += bias[col];
          if (cscale) v *= cscale[col];
          if (mode == 0)      Cf[(size_t)row * ldc + col] = v;
          else if (mode == 1) Cb[(size_t)row * ldc + col] = btrunc(v);
          else                Cb[(size_t)col * ldc + row] = btrunc(v);
        }
      }
    }
  }
}

// ---------------- fused attention ----------------
// 256 blocks (one 16-row tile each, 1/CU), 1024 threads = 16 waves, loop h=0..7.
// ph1: QK^T MFMA -> S bf16 swizzled LDS (wave-private rows in ph2).
// ph2 (3 sweeps, wave-private hist): pass0 sweep (hist hi-byte + row max fused),
//   pass1 sweep (boundary bin), exp sweep (e -> LDS, packed e kept in esave regs).
//   After invZ: am2 (packed f16) updated register-to-register — no ph2.5 LDS re-read.
// ph3: PV MFMA K-split on raw e, scaled by invZ in epilogue; LDS reduce.
#define SROWB 8464                    // 8448 data + 16 pad (odd 16B units -> bank spread)
#define QOFF  (16 * SROWB)            // 135424
#define HOFF  (QOFF + 16 * 72 * 2)    // + 2304 = 137728
#define SMEMSZ (HOFF + 16 * 256 * 4)  // + 16384 = 154112

__global__ __launch_bounds__(1024) void fused_attn(
    const unsigned short* __restrict__ Qbf, const unsigned short* __restrict__ Kbf,
    const unsigned short* __restrict__ Vt, unsigned short* __restrict__ aobf,
    float* __restrict__ attn_mean_out) {
  extern __shared__ char dsm[];
  unsigned short* qt = (unsigned short*)(dsm + QOFF);
  unsigned* hist = (unsigned*)(dsm + HOFF);    // [16 waves][256], wave-private
  const int n0 = blockIdx.x * 16;
  const int t = threadIdx.x;
  const int w = t >> 6, lane = t & 63;
  const int lr = lane & 15, lg = lane >> 4;
  unsigned* hw = hist + w * 256;
  const int r = w;                              // row owned by this wave
  const unsigned swz = (unsigned)((r & 7) << 4);

  __half2 am2[36];
  const __half2 zero2 = __floats2half2_rn(0.f, 0.f);
  #pragma unroll
  for (int j = 0; j < 36; ++j) am2[j] = zero2;

  for (int h = 0; h < NH; ++h) {
    // ---- ph0: Q tile -> LDS (16 x 64, stride 72); one elem per thread ----
    qt[(t >> 6) * 72 + (t & 63)] = Qbf[(size_t)(n0 + (t >> 6)) * DIM + h * HD + (t & 63)];
    __syncthreads();

    // ---- ph1: S = Q @ K^T * 0.125 -> LDS bf16 (swizzled); frag fi = w + 16*f ----
    {
      bf16x8 a0 = *(const bf16x8*)(qt + lr * 72 + lg * 8);
      bf16x8 a1 = *(const bf16x8*)(qt + lr * 72 + 32 + lg * 8);
      #pragma unroll
      for (int f = 0; f < 17; ++f) {
        if (f < 16 || w < 8) {                 // fi < 264
          int m0 = (w + 16 * f) * 16;
          const unsigned short* kp = Kbf + (size_t)(m0 + lr) * DIM + h * HD + lg * 8;
          bf16x8 b0 = *(const bf16x8*)(kp);
          bf16x8 b1 = *(const bf16x8*)(kp + 32);
          f32x4 c = {0.f, 0.f, 0.f, 0.f};
          c = __builtin_amdgcn_mfma_f32_16x16x32_bf16(a0, b0, c, 0, 0, 0);
          c = __builtin_amdgcn_mfma_f32_16x16x32_bf16(a1, b1, c, 0, 0, 0);
          int m = m0 + lr;
          #pragma unroll
          for (int q = 0; q < 4; ++q) {
            int rr = lg * 4 + q;
            *(unsigned short*)(dsm + rr * SROWB + ((2 * m) ^ ((rr & 7) << 4))) = btrunc(c[q] * 0.125f);
          }
        }
      }
    }
    __syncthreads();

    // ---- ph2: 3-sweep select + exp for row r = w; invZ stays in reg ----
    float invZ;
    {
      // pass 0 sweep: high-byte histogram + fused row max
      unsigned maxkey = 0;
      hw[lane] = 0u; hw[lane + 64] = 0u; hw[lane + 128] = 0u; hw[lane + 192] = 0u;
      #pragma unroll
      for (int c = 0; c < 9; ++c) {
        if (c < 8 || lane < 16) {
          uint4 pk4 = *(const uint4*)(dsm + r * SROWB + (((unsigned)(c * 1024 + lane * 16)) ^ swz));
          const unsigned* pw = (const unsigned*)&pk4;
          #pragma unroll
          for (int p2 = 0; p2 < 4; ++p2) {
            unsigned pk = pw[p2];
            int mb = c * 512 + lane * 8 + p2 * 2;
            #pragma unroll
            for (int e = 0; e < 2; ++e) {
              int m = mb + e;
              unsigned u = (e == 0) ? (pk & 0xFFFFu) : (pk >> 16);
              unsigned key = u ^ ((u & 0x8000u) ? 0xFFFFu : 0x8000u);
              if (m < M2 && key > maxkey) maxkey = key;
              if (m >= 2 && m < M2) atomicAdd(&hw[key >> 8], 1u);
            }
          }
        }
      }
      #pragma unroll
      for (int off = 32; off > 0; off >>= 1) {
        unsigned o_ = (unsigned)__shfl_xor((int)maxkey, off, 64);
        if (o_ > maxkey) maxkey = o_;
      }
      float lmax = bton((unsigned short)(maxkey ^ ((maxkey & 0x8000u) ? 0x8000u : 0xFFFFu)));

      unsigned tb, k_rem = KKEEP;
      {
        unsigned c0 = hw[4*lane], c1 = hw[4*lane+1], c2 = hw[4*lane+2], c3 = hw[4*lane+3];
        unsigned nxtv;
        scan_pick(c0, c1, c2, c3, k_rem, lane, tb, nxtv);
        k_rem -= nxtv;
      }

      // pass 1 sweep: boundary-bin low-byte histogram
      hw[lane] = 0u; hw[lane + 64] = 0u; hw[lane + 128] = 0u; hw[lane + 192] = 0u;
      #pragma unroll
      for (int c = 0; c < 9; ++c) {
        if (c < 8 || lane < 16) {
          uint4 pk4 = *(const uint4*)(dsm + r * SROWB + (((unsigned)(c * 1024 + lane * 16)) ^ swz));
          const unsigned* pw = (const unsigned*)&pk4;
          #pragma unroll
          for (int p2 = 0; p2 < 4; ++p2) {
            unsigned pk = pw[p2];
            int mb = c * 512 + lane * 8 + p2 * 2;
            #pragma unroll
            for (int e = 0; e < 2; ++e) {
              int m = mb + e;
              unsigned u = (e == 0) ? (pk & 0xFFFFu) : (pk >> 16);
              unsigned key = u ^ ((u & 0x8000u) ? 0xFFFFu : 0x8000u);
              if (m >= 2 && m < M2 && (key >> 8) == tb) atomicAdd(&hw[key & 255u], 1u);
            }
          }
        }
      }
      unsigned thrkey;
      {
        unsigned c0 = hw[4*lane], c1 = hw[4*lane+1], c2 = hw[4*lane+2], c3 = hw[4*lane+3];
        unsigned bsel, nxtv;
        scan_pick(c0, c1, c2, c3, k_rem, lane, bsel, nxtv);
        thrkey = (tb << 8) | bsel;
      }

      // exp sweep (kept only) + sum; e -> LDS, packed e kept in esave
      unsigned esave[36];
      float lsum = 0.f;
      #pragma unroll
      for (int c = 0; c < 9; ++c) {
        if (c < 8 || lane < 16) {
          char* ap = dsm + r * SROWB + (((unsigned)(c * 1024 + lane * 16)) ^ swz);
          uint4 pk4 = *(const uint4*)ap;
          unsigned* pw = (unsigned*)&pk4;
          #pragma unroll
          for (int p2 = 0; p2 < 4; ++p2) {
            unsigned pk = pw[p2];
            int mb = c * 512 + lane * 8 + p2 * 2;
            unsigned outw = 0;
            #pragma unroll
            for (int e = 0; e < 2; ++e) {
              int m = mb + e;
              unsigned u = (e == 0) ? (pk & 0xFFFFu) : (pk >> 16);
              unsigned key = u ^ ((u & 0x8000u) ? 0xFFFFu : 0x8000u);
              bool kept = (m < 2) || (m < M2 && key >= thrkey);
              float evf = kept ? __expf(bton((unsigned short)u) - lmax) : 0.f;
              unsigned short eb = btrunc(evf);
              lsum += bton(eb);
              outw |= ((unsigned)eb) << (16 * e);
            }
            pw[p2] = outw;
            esave[c * 4 + p2] = outw;
          }
          *(uint4*)ap = pk4;
        } else {
          esave[c * 4 + 0] = 0u; esave[c * 4 + 1] = 0u;
          esave[c * 4 + 2] = 0u; esave[c * 4 + 3] = 0u;
        }
      }
      #pragma unroll
      for (int off = 32; off > 0; off >>= 1) lsum += __shfl_xor(lsum, off, 64);
      invZ = 1.0f / lsum;

      // attn_mean accumulation: pure register update (p = e * invZ)
      #pragma unroll
      for (int j = 0; j < 36; ++j) {
        unsigned pk = esave[j];
        float lo = bton((unsigned short)(pk & 0xFFFFu)) * invZ;
        float hi = bton((unsigned short)(pk >> 16)) * invZ;
        am2[j] = __hadd2(am2[j], __floats2half2_rn(lo, hi));
      }
    }
    __syncthreads();   // all waves' e finalized before PV reads all rows

    // ---- ph3: PV = e @ V (K-split, slice s = w + 16*ks); scale by invZ in epilogue ----
    {
      f32x4 o0 = {0.f,0.f,0.f,0.f}, o1 = o0, o2 = o0, o3 = o0;
      const unsigned short* Vb = Vt + (size_t)(h * HD) * MPAD;
      #pragma unroll
      for (int ks = 0; ks < 9; ++ks) {
        if (ks < 8 || w < 4) {                 // slice < 132
          int kk = (w + 16 * ks) * 32 + lg * 8;
          bf16x8 a = *(const bf16x8*)(dsm + lr * SROWB + ((2 * kk) ^ ((lr & 7) << 4)));
          bf16x8 b0 = *(const bf16x8*)(Vb + (size_t)(lr) * MPAD + kk);
          bf16x8 b1 = *(const bf16x8*)(Vb + (size_t)(16 + lr) * MPAD + kk);
          bf16x8 b2 = *(const bf16x8*)(Vb + (size_t)(32 + lr) * MPAD + kk);
          bf16x8 b3 = *(const bf16x8*)(Vb + (size_t)(48 + lr) * MPAD + kk);
          o0 = __builtin_amdgcn_mfma_f32_16x16x32_bf16(a, b0, o0, 0, 0, 0);
          o1 = __builtin_amdgcn_mfma_f32_16x16x32_bf16(a, b1, o1, 0, 0, 0);
          o2 = __builtin_amdgcn_mfma_f32_16x16x32_bf16(a, b2, o2, 0, 0, 0);
          o3 = __builtin_amdgcn_mfma_f32_16x16x32_bf16(a, b3, o3, 0, 0, 0);
        }
      }
      __syncthreads();   // all waves done reading e
      float* part = (float*)dsm;   // [16][16][64] = 64 KB, overlays S rows
      #pragma unroll
      for (int q = 0; q < 4; q++) {
        int row = lg * 4 + q;
        part[w * 1024 + row * 64 +      lr] = o0[q];
        part[w * 1024 + row * 64 + 16 + lr] = o1[q];
        part[w * 1024 + row * 64 + 32 + lr] = o2[q];
        part[w * 1024 + row * 64 + 48 + lr] = o3[q];
      }
      __syncthreads();
      {
        float s = 0.f;
        #pragma unroll
        for (int ww = 0; ww < 16; ++ww) s += part[ww * 1024 + t];
        aobf[(size_t)(n0 + (t >> 6)) * DIM + h * HD + (t & 63)] = btrunc(s * invZ);
      }
      // next head's post-ph0 barrier protects part reads from S overwrite
    }
  }

  // ---- write attn_mean once (row r = w; am2[c*4+p2] -> m = c*512 + lane*8 + p2*2) ----
  {
    float* dst = attn_mean_out + (size_t)(n0 + r) * M2;
    #pragma unroll
    for (int c = 0; c < 8; ++c) {
      int mbase = c * 512 + lane * 8;
      #pragma unroll
      for (int p2 = 0; p2 < 4; ++p2) {
        float2 v;
        v.x = __low2float(am2[c * 4 + p2])  * 0.125f;
        v.y = __high2float(am2[c * 4 + p2]) * 0.125f;
        *(float2*)(dst + mbase + 2 * p2) = v;
      }
    }
    if (lane == 0) {                           // m 4096, 4097
      dst[4096] = __low2float(am2[32])  * 0.125f;
      dst[4097] = __high2float(am2[32]) * 0.125f;
    }
  }
}

// ---------------- concat(sfbf, bf16(pj)) ----------------
__global__ __launch_bounds__(256) void cat_bf(
    const unsigned short* __restrict__ sfbf, const float* __restrict__ pj,
    unsigned short* __restrict__ cat) {
  int i4 = blockIdx.x * 256 + threadIdx.x;
  if (i4 >= (4096 * 1024) / 4) return;
  int idx = i4 * 4;
  int n = idx >> 10, c = idx & 1023;
  if (c < 512) {
    *(ushort4*)(cat + idx) = *(const ushort4*)(sfbf + (size_t)n * 512 + c);
  } else {
    float4 v = *(const float4*)(pj + (size_t)n * 512 + (c - 512));
    ushort4 o; o.x = btrunc(v.x); o.y = btrunc(v.y); o.z = btrunc(v.z); o.w = btrunc(v.w);
    *(ushort4*)(cat + idx) = o;
  }
}

// ---------------- gate, residual, RMSNorm, gate partial sums ----------------
__global__ __launch_bounds__(256) void final_kernel(
    const float* __restrict__ sf, const float* __restrict__ pj,
    const float* __restrict__ gl, const float* __restrict__ norm_w,
    float* __restrict__ outf, float* __restrict__ gpart) {
  int n = blockIdx.x, t = threadIdx.x;
  __shared__ float red[256];
  size_t base = (size_t)n * 512;
  float g0 = sigmoidf_(gl[base + t]);
  float g1 = sigmoidf_(gl[base + 256 + t]);
  float x0 = sf[base + t], x1 = sf[base + 256 + t];
  float p0 = pj[base + t], p1 = pj[base + 256 + t];
  float gr0 = x0 + g0 * p0, gr1 = x1 + g1 * p1;

  red[t] = g0 + g1;
  __syncthreads();
  for (int off = 128; off > 0; off >>= 1) {
    if (t < off) red[t] += red[t + off];
    __syncthreads();
  }
  if (t == 0) gpart[n] = red[0];
  __syncthreads();

  red[t] = gr0 * gr0 + gr1 * gr1;
  __syncthreads();
  for (int off = 128; off > 0; off >>= 1) {
    if (t < off) red[t] += red[t + off];
    __syncthreads();
  }
  float rms = rsqrtf(red[0] * (1.0f / 512.0f) + 1e-6f);
  outf[base + t] = gr0 * rms * norm_w[t];
  outf[base + 256 + t] = gr1 * rms * norm_w[256 + t];
}

__global__ __launch_bounds__(256) void gate_reduce(
    const float* __restrict__ gpart, float* __restrict__ out_scalar) {
  __shared__ float red[256];
  int t = threadIdx.x;
  float s = 0.f;
  for (int i = t; i < 4096; i += 256) s += gpart[i];
  red[t] = s;
  __syncthreads();
  for (int off = 128; off > 0; off >>= 1) {
    if (t < off) red[t] += red[t + off];
    __syncthreads();
  }
  if (t == 0) out_scalar[0] = red[0] * (1.0f / (4096.0f * 512.0f));
}

extern "C" void kernel_launch(void* const* d_in, const int* in_sizes, int n_in,
                              void* d_out, int out_size, void* d_ws, size_t ws_size,
                              hipStream_t stream) {
  const float* sf  = (const float*)d_in[0];
  const float* zp  = (const float*)d_in[1];
  const float* zs  = (const float*)d_in[2];
  const float* Wq  = (const float*)d_in[3];
  const float* Wk  = (const float*)d_in[4];
  const float* Wv  = (const float*)d_in[5];
  const float* Wg  = (const float*)d_in[6];
  const float* bg  = (const float*)d_in[7];
  const float* Wag = (const float*)d_in[8];
  const float* bag = (const float*)d_in[9];
  const float* nw  = (const float*)d_in[10];
  const float* Wo  = (const float*)d_in[11];
  const float* bo  = (const float*)d_in[12];

  float* out  = (float*)d_out;
  float* outF = out + OUT_F;
  float* outR = out + OUT_R;
  float* outG = out + OUT_G;
  float* outA = out + OUT_A;

  // workspace layout (bytes)
  char* W = (char*)d_ws;
  float*          regime  = (float*)(W + 0);                 // 2048
  float*          gpart   = (float*)(W + 2048);              // 16384
  unsigned short* sfbf    = (unsigned short*)(W + 18432);    // 4,194,304
  unsigned short* nodesbf = (unsigned short*)(W + 4212736);  // 4,196,352
  unsigned short* Qbf     = (unsigned short*)(W + 8409088);  // 4,194,304
  unsigned short* Kbf     = (unsigned short*)(W + 12603392); // 4,325,376 (4224 rows)
  unsigned short* Vt      = (unsigned short*)(W + 16928768); // 4,325,376 (512 x 4224)
  unsigned short* aobf    = (unsigned short*)(W + 21254144); // 4,194,304
  unsigned short* catbf   = (unsigned short*)(W + 25448448); // 8,388,608
  unsigned short* Wqbf    = (unsigned short*)(W + 33837056); // 524,288
  unsigned short* Wkbf    = (unsigned short*)(W + 34361344); // 524,288
  unsigned short* Wvbf    = (unsigned short*)(W + 34885632); // 524,288
  unsigned short* Wobf    = (unsigned short*)(W + 35409920); // 524,288
  unsigned short* Wagbf   = (unsigned short*)(W + 35934208); // 1,048,576
  float*          pj      = (float*)(W + 36982784);          // 8,388,608 -> 45,371,392
  float*          gl      = (float*)(W + 4212736);           // alias over nodesbf+Qbf (dead by then)

  hipFuncSetAttribute((const void*)fused_attn,
                      hipFuncAttributeMaxDynamicSharedMemorySize, SMEMSZ);

  // --- small prep ---
  regime_kernel<<<1, 256, 0, stream>>>(zp, zs, Wg, bg, regime);
  conv_bf<<<2048, 256, 0, stream>>>(sf, sfbf, 524288);
  build_nodes_bf<<<2049, 256, 0, stream>>>(zp, zs, sf, nodesbf);
  conv_bf<<<256, 256, 0, stream>>>(Wq, Wqbf, 65536);
  conv_bf<<<256, 256, 0, stream>>>(Wk, Wkbf, 65536);
  conv_bf<<<256, 256, 0, stream>>>(Wv, Wvbf, 65536);
  conv_bf<<<256, 256, 0, stream>>>(Wo, Wobf, 65536);
  conv_bf<<<512, 256, 0, stream>>>(Wag, Wagbf, 131072);
  hipMemsetAsync(Kbf, 0, 4325376, stream);
  hipMemsetAsync(Vt, 0, 4325376, stream);

  // --- projections (bf16 MFMA) ---
  gemm_bf16<<<dim3(4, 32), 256, 0, stream>>>(sfbf, Wqbf, nullptr, regime, nullptr, Qbf,
                                             4096, 512, 512, 512, 512, 512, 1.0f, 1);
  gemm_bf16<<<dim3(4, 33), 256, 0, stream>>>(nodesbf, Wkbf, nullptr, nullptr, nullptr, Kbf,
                                             M2, 512, 512, 512, 512, 512, 1.0f, 1);
  gemm_bf16<<<dim3(4, 33), 256, 0, stream>>>(nodesbf, Wvbf, nullptr, nullptr, nullptr, Vt,
                                             M2, 512, 512, 512, 512, MPAD, 1.0f, 2);

  // --- raw_scores = (Q @ K^T) * (0.125/8) over full 512 dims ---
  gemm_bf16<<<dim3(33, 32), 256, 0, stream>>>(Qbf, Kbf, nullptr, nullptr, outR, nullptr,
                                              4096, M2, 512, 512, 512, M2, 0.015625f, 0);

  // --- fused attention (256 blocks, 1024 threads, no atomics to global) ---
  fused_attn<<<256, 1024, SMEMSZ, stream>>>(Qbf, Kbf, Vt, aobf, outA);

  // --- output projection + gate + final ---
  gemm_bf16<<<dim3(4, 32), 256, 0, stream>>>(aobf, Wobf, bo, nullptr, pj, nullptr,
                                             4096, 512, 512, 512, 512, 512, 1.0f, 0);
  cat_bf<<<4096, 256, 0, stream>>>(sfbf, pj, catbf);
  gemm_bf16<<<dim3(4, 32), 256, 0, stream>>>(catbf, Wagbf, bag, nullptr, gl, nullptr,
                                             4096, 512, 1024, 1024, 1024, 512, 1.0f, 0);
  final_kernel<<<4096, 256, 0, stream>>>(sf, pj, gl, nw, outF, gpart);
  gate_reduce<<<1, 256, 0, stream>>>(gpart, outG);
}

// Round 10
// 1094.810 us; speedup vs baseline: 1.2042x; 1.0018x over previous
//
#include <hip/hip_runtime.h>
#include <hip/hip_fp16.h>
#include <math.h>

// Problem constants
#define NS 4096      // N stocks
#define DIM 512      // D
#define NH 8         // heads
#define HD 64        // head dim
#define M2 4098      // N + 2 nodes
#define MPAD 4224    // m padded to multiple of 32 (264 frags of 16)
#define KKEEP 2048u  // top-k keep

// Output layout (floats): final_out | raw_scores | gate_mean | attn_mean
#define OUT_F 0
#define OUT_R 2097152          // 4096*512
#define OUT_G 18882560         // + 4096*4098
#define OUT_A 18882561

typedef __attribute__((ext_vector_type(8))) short bf16x8;
typedef __attribute__((ext_vector_type(4))) float f32x4;

__device__ __forceinline__ float sigmoidf_(float x) { return 1.0f / (1.0f + __expf(-x)); }

__device__ __forceinline__ unsigned short btrunc(float f) {   // f32 -> bf16 RNE
  unsigned u = __float_as_uint(f);
  u = u + 0x7FFFu + ((u >> 16) & 1u);
  return (unsigned short)(u >> 16);
}
__device__ __forceinline__ float bton(unsigned short h) {
  return __uint_as_float(((unsigned)h) << 16);
}

// wave suffix-scan over 256 bins (4/lane) and rank pick; returns bin + count-strictly-above
__device__ __forceinline__ void scan_pick(unsigned c0, unsigned c1, unsigned c2, unsigned c3,
                                          unsigned k_rem, int lane,
                                          unsigned& bsel_out, unsigned& nxt_out) {
  unsigned run = c0 + c1 + c2 + c3;
  #pragma unroll
  for (int off = 1; off < 64; off <<= 1) {
    unsigned o_ = __shfl_down(run, off, 64);
    if (lane + off < 64) run += o_;
  }
  unsigned s0 = run, s1 = run - c0, s2 = s1 - c1, s3 = s2 - c2, s4 = s3 - c3;
  int which = -1;
  if      (s0 >= k_rem && s1 < k_rem) which = 0;
  else if (s1 >= k_rem && s2 < k_rem) which = 1;
  else if (s2 >= k_rem && s3 < k_rem) which = 2;
  else if (s3 >= k_rem && s4 < k_rem) which = 3;
  unsigned long long bal = __ballot(which >= 0);
  int src = (int)__ffsll(bal) - 1;
  unsigned nxtv = (which == 0) ? s1 : (which == 1) ? s2 : (which == 2) ? s3 : s4;
  unsigned bsel = (unsigned)(4 * lane + (which < 0 ? 0 : which));
  bsel_out = (unsigned)__shfl((int)bsel, src, 64);
  nxt_out  = (unsigned)__shfl((int)nxtv, src, 64);
}

// ---------------- regime_mod = sigmoid([zp,zs] @ Wg.T + bg) ----------------
__global__ __launch_bounds__(256) void regime_kernel(
    const float* __restrict__ zp, const float* __restrict__ zs,
    const float* __restrict__ Wg, const float* __restrict__ bg,
    float* __restrict__ regime) {
  __shared__ float zc[1024];
  int t = threadIdx.x;
  for (int i = t; i < 512; i += 256) { zc[i] = zp[i]; zc[512 + i] = zs[i]; }
  __syncthreads();
  for (int j = t; j < 512; j += 256) {
    const float4* w = (const float4*)(Wg + (size_t)j * 1024);
    float acc = 0.f;
    #pragma unroll 8
    for (int i = 0; i < 256; i++) {
      float4 wv = w[i];
      acc += wv.x * zc[4*i] + wv.y * zc[4*i+1] + wv.z * zc[4*i+2] + wv.w * zc[4*i+3];
    }
    regime[j] = sigmoidf_(acc + bg[j]);
  }
}

// ---------------- generic f32 -> bf16 convert ----------------
__global__ __launch_bounds__(256) void conv_bf(
    const float* __restrict__ src, unsigned short* __restrict__ dst, int n4) {
  int i4 = blockIdx.x * 256 + threadIdx.x;
  if (i4 >= n4) return;
  float4 v = *(const float4*)(src + (size_t)i4 * 4);
  ushort4 o; o.x = btrunc(v.x); o.y = btrunc(v.y); o.z = btrunc(v.z); o.w = btrunc(v.w);
  *(ushort4*)(dst + (size_t)i4 * 4) = o;
}

// ---------------- nodes = concat(zp, zs, sf) in bf16 ----------------
__global__ __launch_bounds__(256) void build_nodes_bf(
    const float* __restrict__ zp, const float* __restrict__ zs,
    const float* __restrict__ sf, unsigned short* __restrict__ nb) {
  int i4 = blockIdx.x * 256 + threadIdx.x;
  if (i4 >= (M2 * DIM) / 4) return;
  int idx = i4 * 4;
  int m = idx >> 9, c = idx & 511;
  const float* src = (m == 0) ? (zp + c) : (m == 1) ? (zs + c)
                               : (sf + (size_t)(m - 2) * 512 + c);
  float4 v = *(const float4*)src;
  ushort4 o; o.x = btrunc(v.x); o.y = btrunc(v.y); o.z = btrunc(v.z); o.w = btrunc(v.w);
  *(ushort4*)(nb + idx) = o;
}

// ---------------- bf16 MFMA GEMM: C = (A[M][K] @ B[N][K]^T * scale + bias) * cscale ----------------
// 128x128 tile, 256 threads (4 waves in 2x2), BK=32.
// mode 0: C fp32 [M][ldc]; mode 1: C bf16 [M][ldc]; mode 2: C bf16 transposed [N][ldc] (C[col][row]).
#define LSTR 40
__global__ __launch_bounds__(256) void gemm_bf16(
    const unsigned short* __restrict__ A, const unsigned short* __restrict__ B,
    const float* __restrict__ bias, const float* __restrict__ cscale,
    float* __restrict__ Cf, unsigned short* __restrict__ Cb,
    int M, int N, int K, int lda, int ldb, int ldc, float scale, int mode) {
  __shared__ unsigned short As[128 * LSTR];
  __shared__ unsigned short Bs[128 * LSTR];
  const int t = threadIdx.x;
  const int w = t >> 6, lane = t & 63;
  const int wr = w >> 1, wc = w & 1;
  const int lr = lane & 15, lg = lane >> 4;
  const int bm = blockIdx.y * 128, bn = blockIdx.x * 128;
  f32x4 acc[4][4] = {};
  for (int k0 = 0; k0 < K; k0 += 32) {
    #pragma unroll
    for (int i = 0; i < 2; i++) {
      int q = t + i * 256;
      int row = q >> 2;
      int ko = (q & 3) * 8;
      bf16x8 av = {};
      int gr = bm + row;
      if (gr < M) av = *(const bf16x8*)(A + (size_t)gr * lda + k0 + ko);
      *(bf16x8*)(As + row * LSTR + ko) = av;
      bf16x8 bv = {};
      int gbr = bn + row;
      if (gbr < N) bv = *(const bf16x8*)(B + (size_t)gbr * ldb + k0 + ko);
      *(bf16x8*)(Bs + row * LSTR + ko) = bv;
    }
    __syncthreads();
    {
      bf16x8 af[4], bfr[4];
      #pragma unroll
      for (int i = 0; i < 4; i++)
        af[i] = *(const bf16x8*)(As + (64 * wr + 16 * i + lr) * LSTR + lg * 8);
      #pragma unroll
      for (int j = 0; j < 4; j++)
        bfr[j] = *(const bf16x8*)(Bs + (64 * wc + 16 * j + lr) * LSTR + lg * 8);
      #pragma unroll
      for (int i = 0; i < 4; i++)
        #pragma unroll
        for (int j = 0; j < 4; j++)
          acc[i][j] = __builtin_amdgcn_mfma_f32_16x16x32_bf16(af[i], bfr[j], acc[i][j], 0, 0, 0);
    }
    __syncthreads();
  }
  // epilogue
  #pragma unroll
  for (int i = 0; i < 4; i++) {
    #pragma unroll
    for (int j = 0; j < 4; j++) {
      #pragma unroll
      for (int q = 0; q < 4; q++) {
        int row = bm + 64 * wr + 16 * i + lg * 4 + q;
        int col = bn + 64 * wc + 16 * j + lr;
        if (row < M && col < N) {
          float v = acc[i][j][q] * scale;
          if (bias)   v += bias[col];
          if (cscale) v *= cscale[col];
          if (mode == 0)      Cf[(size_t)row * ldc + col] = v;
          else if (mode == 1) Cb[(size_t)row * ldc + col] = btrunc(v);
          else                Cb[(size_t)col * ldc + row] = btrunc(v);
        }
      }
    }
  }
}

// ---------------- fused attention ----------------
// 256 blocks (one 16-row tile each, 1/CU), 1024 threads = 16 waves, loop h=0..7.
// waves_per_eu(4,4) pins the compiler to a 128-VGPR budget (16 waves = 4/EU,
// LDS-capped at 1 block/CU anyway) so am2/esave stay in registers — no scratch.
// ph1: QK^T MFMA -> S bf16 swizzled LDS (wave-private rows in ph2).
// ph2 (3 sweeps, wave-private hist): pass0 sweep (hist hi-byte + row max fused),
//   pass1 sweep (boundary bin), exp sweep (e -> LDS, packed e kept in esave regs).
//   After invZ: am2 (packed f16) updated register-to-register.
// ph3: PV MFMA K-split on raw e, scaled by invZ in epilogue; LDS reduce.
#define SROWB 8464                    // 8448 data + 16 pad (odd 16B units -> bank spread)
#define QOFF  (16 * SROWB)            // 135424
#define HOFF  (QOFF + 16 * 72 * 2)    // + 2304 = 137728
#define SMEMSZ (HOFF + 16 * 256 * 4)  // + 16384 = 154112

__global__ __launch_bounds__(1024)
__attribute__((amdgpu_waves_per_eu(4, 4)))
void fused_attn(
    const unsigned short* __restrict__ Qbf, const unsigned short* __restrict__ Kbf,
    const unsigned short* __restrict__ Vt, unsigned short* __restrict__ aobf,
    float* __restrict__ attn_mean_out) {
  extern __shared__ char dsm[];
  unsigned short* qt = (unsigned short*)(dsm + QOFF);
  unsigned* hist = (unsigned*)(dsm + HOFF);    // [16 waves][256], wave-private
  const int n0 = blockIdx.x * 16;
  const int t = threadIdx.x;
  const int w = t >> 6, lane = t & 63;
  const int lr = lane & 15, lg = lane >> 4;
  unsigned* hw = hist + w * 256;
  const int r = w;                              // row owned by this wave
  const unsigned swz = (unsigned)((r & 7) << 4);

  __half2 am2[36];
  const __half2 zero2 = __floats2half2_rn(0.f, 0.f);
  #pragma unroll
  for (int j = 0; j < 36; ++j) am2[j] = zero2;

  for (int h = 0; h < NH; ++h) {
    // ---- ph0: Q tile -> LDS (16 x 64, stride 72); one elem per thread ----
    qt[(t >> 6) * 72 + (t & 63)] = Qbf[(size_t)(n0 + (t >> 6)) * DIM + h * HD + (t & 63)];
    __syncthreads();

    // ---- ph1: S = Q @ K^T * 0.125 -> LDS bf16 (swizzled); frag fi = w + 16*f ----
    {
      bf16x8 a0 = *(const bf16x8*)(qt + lr * 72 + lg * 8);
      bf16x8 a1 = *(const bf16x8*)(qt + lr * 72 + 32 + lg * 8);
      #pragma unroll
      for (int f = 0; f < 17; ++f) {
        if (f < 16 || w < 8) {                 // fi < 264
          int m0 = (w + 16 * f) * 16;
          const unsigned short* kp = Kbf + (size_t)(m0 + lr) * DIM + h * HD + lg * 8;
          bf16x8 b0 = *(const bf16x8*)(kp);
          bf16x8 b1 = *(const bf16x8*)(kp + 32);
          f32x4 c = {0.f, 0.f, 0.f, 0.f};
          c = __builtin_amdgcn_mfma_f32_16x16x32_bf16(a0, b0, c, 0, 0, 0);
          c = __builtin_amdgcn_mfma_f32_16x16x32_bf16(a1, b1, c, 0, 0, 0);
          int m = m0 + lr;
          #pragma unroll
          for (int q = 0; q < 4; ++q) {
            int rr = lg * 4 + q;
            *(unsigned short*)(dsm + rr * SROWB + ((2 * m) ^ ((rr & 7) << 4))) = btrunc(c[q] * 0.125f);
          }
        }
      }
    }
    __syncthreads();

    // ---- ph2: 3-sweep select + exp for row r = w; invZ stays in reg ----
    float invZ;
    {
      // pass 0 sweep: high-byte histogram + fused row max
      unsigned maxkey = 0;
      hw[lane] = 0u; hw[lane + 64] = 0u; hw[lane + 128] = 0u; hw[lane + 192] = 0u;
      #pragma unroll
      for (int c = 0; c < 9; ++c) {
        if (c < 8 || lane < 16) {
          uint4 pk4 = *(const uint4*)(dsm + r * SROWB + (((unsigned)(c * 1024 + lane * 16)) ^ swz));
          const unsigned* pw = (const unsigned*)&pk4;
          #pragma unroll
          for (int p2 = 0; p2 < 4; ++p2) {
            unsigned pk = pw[p2];
            int mb = c * 512 + lane * 8 + p2 * 2;
            #pragma unroll
            for (int e = 0; e < 2; ++e) {
              int m = mb + e;
              unsigned u = (e == 0) ? (pk & 0xFFFFu) : (pk >> 16);
              unsigned key = u ^ ((u & 0x8000u) ? 0xFFFFu : 0x8000u);
              if (m < M2 && key > maxkey) maxkey = key;
              if (m >= 2 && m < M2) atomicAdd(&hw[key >> 8], 1u);
            }
          }
        }
      }
      #pragma unroll
      for (int off = 32; off > 0; off >>= 1) {
        unsigned o_ = (unsigned)__shfl_xor((int)maxkey, off, 64);
        if (o_ > maxkey) maxkey = o_;
      }
      float lmax = bton((unsigned short)(maxkey ^ ((maxkey & 0x8000u) ? 0x8000u : 0xFFFFu)));

      unsigned tb, k_rem = KKEEP;
      {
        unsigned c0 = hw[4*lane], c1 = hw[4*lane+1], c2 = hw[4*lane+2], c3 = hw[4*lane+3];
        unsigned nxtv;
        scan_pick(c0, c1, c2, c3, k_rem, lane, tb, nxtv);
        k_rem -= nxtv;
      }

      // pass 1 sweep: boundary-bin low-byte histogram
      hw[lane] = 0u; hw[lane + 64] = 0u; hw[lane + 128] = 0u; hw[lane + 192] = 0u;
      #pragma unroll
      for (int c = 0; c < 9; ++c) {
        if (c < 8 || lane < 16) {
          uint4 pk4 = *(const uint4*)(dsm + r * SROWB + (((unsigned)(c * 1024 + lane * 16)) ^ swz));
          const unsigned* pw = (const unsigned*)&pk4;
          #pragma unroll
          for (int p2 = 0; p2 < 4; ++p2) {
            unsigned pk = pw[p2];
            int mb = c * 512 + lane * 8 + p2 * 2;
            #pragma unroll
            for (int e = 0; e < 2; ++e) {
              int m = mb + e;
              unsigned u = (e == 0) ? (pk & 0xFFFFu) : (pk >> 16);
              unsigned key = u ^ ((u & 0x8000u) ? 0xFFFFu : 0x8000u);
              if (m >= 2 && m < M2 && (key >> 8) == tb) atomicAdd(&hw[key & 255u], 1u);
            }
          }
        }
      }
      unsigned thrkey;
      {
        unsigned c0 = hw[4*lane], c1 = hw[4*lane+1], c2 = hw[4*lane+2], c3 = hw[4*lane+3];
        unsigned bsel, nxtv;
        scan_pick(c0, c1, c2, c3, k_rem, lane, bsel, nxtv);
        thrkey = (tb << 8) | bsel;
      }

      // exp sweep (kept only) + sum; e -> LDS, packed e kept in esave
      unsigned esave[36];
      float lsum = 0.f;
      #pragma unroll
      for (int c = 0; c < 9; ++c) {
        if (c < 8 || lane < 16) {
          char* ap = dsm + r * SROWB + (((unsigned)(c * 1024 + lane * 16)) ^ swz);
          uint4 pk4 = *(const uint4*)ap;
          unsigned* pw = (unsigned*)&pk4;
          #pragma unroll
          for (int p2 = 0; p2 < 4; ++p2) {
            unsigned pk = pw[p2];
            int mb = c * 512 + lane * 8 + p2 * 2;
            unsigned outw = 0;
            #pragma unroll
            for (int e = 0; e < 2; ++e) {
              int m = mb + e;
              unsigned u = (e == 0) ? (pk & 0xFFFFu) : (pk >> 16);
              unsigned key = u ^ ((u & 0x8000u) ? 0xFFFFu : 0x8000u);
              bool kept = (m < 2) || (m < M2 && key >= thrkey);
              float evf = kept ? __expf(bton((unsigned short)u) - lmax) : 0.f;
              unsigned short eb = btrunc(evf);
              lsum += bton(eb);
              outw |= ((unsigned)eb) << (16 * e);
            }
            pw[p2] = outw;
            esave[c * 4 + p2] = outw;
          }
          *(uint4*)ap = pk4;
        } else {
          esave[c * 4 + 0] = 0u; esave[c * 4 + 1] = 0u;
          esave[c * 4 + 2] = 0u; esave[c * 4 + 3] = 0u;
        }
      }
      #pragma unroll
      for (int off = 32; off > 0; off >>= 1) lsum += __shfl_xor(lsum, off, 64);
      invZ = 1.0f / lsum;

      // attn_mean accumulation: pure register update (p = e * invZ)
      #pragma unroll
      for (int j = 0; j < 36; ++j) {
        unsigned pk = esave[j];
        float lo = bton((unsigned short)(pk & 0xFFFFu)) * invZ;
        float hi = bton((unsigned short)(pk >> 16)) * invZ;
        am2[j] = __hadd2(am2[j], __floats2half2_rn(lo, hi));
      }
    }
    __syncthreads();   // all waves' e finalized before PV reads all rows

    // ---- ph3: PV = e @ V (K-split, slice s = w + 16*ks); scale by invZ in epilogue ----
    {
      f32x4 o0 = {0.f,0.f,0.f,0.f}, o1 = o0, o2 = o0, o3 = o0;
      const unsigned short* Vb = Vt + (size_t)(h * HD) * MPAD;
      #pragma unroll
      for (int ks = 0; ks < 9; ++ks) {
        if (ks < 8 || w < 4) {                 // slice < 132
          int kk = (w + 16 * ks) * 32 + lg * 8;
          bf16x8 a = *(const bf16x8*)(dsm + lr * SROWB + ((2 * kk) ^ ((lr & 7) << 4)));
          bf16x8 b0 = *(const bf16x8*)(Vb + (size_t)(lr) * MPAD + kk);
          bf16x8 b1 = *(const bf16x8*)(Vb + (size_t)(16 + lr) * MPAD + kk);
          bf16x8 b2 = *(const bf16x8*)(Vb + (size_t)(32 + lr) * MPAD + kk);
          bf16x8 b3 = *(const bf16x8*)(Vb + (size_t)(48 + lr) * MPAD + kk);
          o0 = __builtin_amdgcn_mfma_f32_16x16x32_bf16(a, b0, o0, 0, 0, 0);
          o1 = __builtin_amdgcn_mfma_f32_16x16x32_bf16(a, b1, o1, 0, 0, 0);
          o2 = __builtin_amdgcn_mfma_f32_16x16x32_bf16(a, b2, o2, 0, 0, 0);
          o3 = __builtin_amdgcn_mfma_f32_16x16x32_bf16(a, b3, o3, 0, 0, 0);
        }
      }
      __syncthreads();   // all waves done reading e
      float* part = (float*)dsm;   // [16][16][64] = 64 KB, overlays S rows
      #pragma unroll
      for (int q = 0; q < 4; q++) {
        int row = lg * 4 + q;
        part[w * 1024 + row * 64 +      lr] = o0[q];
        part[w * 1024 + row * 64 + 16 + lr] = o1[q];
        part[w * 1024 + row * 64 + 32 + lr] = o2[q];
        part[w * 1024 + row * 64 + 48 + lr] = o3[q];
      }
      __syncthreads();
      {
        float s = 0.f;
        #pragma unroll
        for (int ww = 0; ww < 16; ++ww) s += part[ww * 1024 + t];
        aobf[(size_t)(n0 + (t >> 6)) * DIM + h * HD + (t & 63)] = btrunc(s * invZ);
      }
      // next head's post-ph0 barrier protects part reads from S overwrite
    }
  }

  // ---- write attn_mean once (row r = w; am2[c*4+p2] -> m = c*512 + lane*8 + p2*2) ----
  {
    float* dst = attn_mean_out + (size_t)(n0 + r) * M2;
    #pragma unroll
    for (int c = 0; c < 8; ++c) {
      int mbase = c * 512 + lane * 8;
      #pragma unroll
      for (int p2 = 0; p2 < 4; ++p2) {
        float2 v;
        v.x = __low2float(am2[c * 4 + p2])  * 0.125f;
        v.y = __high2float(am2[c * 4 + p2]) * 0.125f;
        *(float2*)(dst + mbase + 2 * p2) = v;
      }
    }
    if (lane == 0) {                           // m 4096, 4097
      dst[4096] = __low2float(am2[32])  * 0.125f;
      dst[4097] = __high2float(am2[32]) * 0.125f;
    }
  }
}

// ---------------- concat(sfbf, bf16(pj)) ----------------
__global__ __launch_bounds__(256) void cat_bf(
    const unsigned short* __restrict__ sfbf, const float* __restrict__ pj,
    unsigned short* __restrict__ cat) {
  int i4 = blockIdx.x * 256 + threadIdx.x;
  if (i4 >= (4096 * 1024) / 4) return;
  int idx = i4 * 4;
  int n = idx >> 10, c = idx & 1023;
  if (c < 512) {
    *(ushort4*)(cat + idx) = *(const ushort4*)(sfbf + (size_t)n * 512 + c);
  } else {
    float4 v = *(const float4*)(pj + (size_t)n * 512 + (c - 512));
    ushort4 o; o.x = btrunc(v.x); o.y = btrunc(v.y); o.z = btrunc(v.z); o.w = btrunc(v.w);
    *(ushort4*)(cat + idx) = o;
  }
}

// ---------------- gate, residual, RMSNorm, gate partial sums ----------------
__global__ __launch_bounds__(256) void final_kernel(
    const float* __restrict__ sf, const float* __restrict__ pj,
    const float* __restrict__ gl, const float* __restrict__ norm_w,
    float* __restrict__ outf, float* __restrict__ gpart) {
  int n = blockIdx.x, t = threadIdx.x;
  __shared__ float red[256];
  size_t base = (size_t)n * 512;
  float g0 = sigmoidf_(gl[base + t]);
  float g1 = sigmoidf_(gl[base + 256 + t]);
  float x0 = sf[base + t], x1 = sf[base + 256 + t];
  float p0 = pj[base + t], p1 = pj[base + 256 + t];
  float gr0 = x0 + g0 * p0, gr1 = x1 + g1 * p1;

  red[t] = g0 + g1;
  __syncthreads();
  for (int off = 128; off > 0; off >>= 1) {
    if (t < off) red[t] += red[t + off];
    __syncthreads();
  }
  if (t == 0) gpart[n] = red[0];
  __syncthreads();

  red[t] = gr0 * gr0 + gr1 * gr1;
  __syncthreads();
  for (int off = 128; off > 0; off >>= 1) {
    if (t < off) red[t] += red[t + off];
    __syncthreads();
  }
  float rms = rsqrtf(red[0] * (1.0f / 512.0f) + 1e-6f);
  outf[base + t] = gr0 * rms * norm_w[t];
  outf[base + 256 + t] = gr1 * rms * norm_w[256 + t];
}

__global__ __launch_bounds__(256) void gate_reduce(
    const float* __restrict__ gpart, float* __restrict__ out_scalar) {
  __shared__ float red[256];
  int t = threadIdx.x;
  float s = 0.f;
  for (int i = t; i < 4096; i += 256) s += gpart[i];
  red[t] = s;
  __syncthreads();
  for (int off = 128; off > 0; off >>= 1) {
    if (t < off) red[t] += red[t + off];
    __syncthreads();
  }
  if (t == 0) out_scalar[0] = red[0] * (1.0f / (4096.0f * 512.0f));
}

extern "C" void kernel_launch(void* const* d_in, const int* in_sizes, int n_in,
                              void* d_out, int out_size, void* d_ws, size_t ws_size,
                              hipStream_t stream) {
  const float* sf  = (const float*)d_in[0];
  const float* zp  = (const float*)d_in[1];
  const float* zs  = (const float*)d_in[2];
  const float* Wq  = (const float*)d_in[3];
  const float* Wk  = (const float*)d_in[4];
  const float* Wv  = (const float*)d_in[5];
  const float* Wg  = (const float*)d_in[6];
  const float* bg  = (const float*)d_in[7];
  const float* Wag = (const float*)d_in[8];
  const float* bag = (const float*)d_in[9];
  const float* nw  = (const float*)d_in[10];
  const float* Wo  = (const float*)d_in[11];
  const float* bo  = (const float*)d_in[12];

  float* out  = (float*)d_out;
  float* outF = out + OUT_F;
  float* outR = out + OUT_R;
  float* outG = out + OUT_G;
  float* outA = out + OUT_A;

  // workspace layout (bytes)
  char* W = (char*)d_ws;
  float*          regime  = (float*)(W + 0);                 // 2048
  float*          gpart   = (float*)(W + 2048);              // 16384
  unsigned short* sfbf    = (unsigned short*)(W + 18432);    // 4,194,304
  unsigned short* nodesbf = (unsigned short*)(W + 4212736);  // 4,196,352
  unsigned short* Qbf     = (unsigned short*)(W + 8409088);  // 4,194,304
  unsigned short* Kbf     = (unsigned short*)(W + 12603392); // 4,325,376 (4224 rows)
  unsigned short* Vt      = (unsigned short*)(W + 16928768); // 4,325,376 (512 x 4224)
  unsigned short* aobf    = (unsigned short*)(W + 21254144); // 4,194,304
  unsigned short* catbf   = (unsigned short*)(W + 25448448); // 8,388,608
  unsigned short* Wqbf    = (unsigned short*)(W + 33837056); // 524,288
  unsigned short* Wkbf    = (unsigned short*)(W + 34361344); // 524,288
  unsigned short* Wvbf    = (unsigned short*)(W + 34885632); // 524,288
  unsigned short* Wobf    = (unsigned short*)(W + 35409920); // 524,288
  unsigned short* Wagbf   = (unsigned short*)(W + 35934208); // 1,048,576
  float*          pj      = (float*)(W + 36982784);          // 8,388,608 -> 45,371,392
  float*          gl      = (float*)(W + 4212736);           // alias over nodesbf+Qbf (dead by then)

  hipFuncSetAttribute((const void*)fused_attn,
                      hipFuncAttributeMaxDynamicSharedMemorySize, SMEMSZ);

  // --- small prep ---
  regime_kernel<<<1, 256, 0, stream>>>(zp, zs, Wg, bg, regime);
  conv_bf<<<2048, 256, 0, stream>>>(sf, sfbf, 524288);
  build_nodes_bf<<<2049, 256, 0, stream>>>(zp, zs, sf, nodesbf);
  conv_bf<<<256, 256, 0, stream>>>(Wq, Wqbf, 65536);
  conv_bf<<<256, 256, 0, stream>>>(Wk, Wkbf, 65536);
  conv_bf<<<256, 256, 0, stream>>>(Wv, Wvbf, 65536);
  conv_bf<<<256, 256, 0, stream>>>(Wo, Wobf, 65536);
  conv_bf<<<512, 256, 0, stream>>>(Wag, Wagbf, 131072);
  hipMemsetAsync(Kbf, 0, 4325376, stream);
  hipMemsetAsync(Vt, 0, 4325376, stream);

  // --- projections (bf16 MFMA) ---
  gemm_bf16<<<dim3(4, 32), 256, 0, stream>>>(sfbf, Wqbf, nullptr, regime, nullptr, Qbf,
                                             4096, 512, 512, 512, 512, 512, 1.0f, 1);
  gemm_bf16<<<dim3(4, 33), 256, 0, stream>>>(nodesbf, Wkbf, nullptr, nullptr, nullptr, Kbf,
                                             M2, 512, 512, 512, 512, 512, 1.0f, 1);
  gemm_bf16<<<dim3(4, 33), 256, 0, stream>>>(nodesbf, Wvbf, nullptr, nullptr, nullptr, Vt,
                                             M2, 512, 512, 512, 512, MPAD, 1.0f, 2);

  // --- raw_scores = (Q @ K^T) * (0.125/8) over full 512 dims ---
  gemm_bf16<<<dim3(33, 32), 256, 0, stream>>>(Qbf, Kbf, nullptr, nullptr, outR, nullptr,
                                              4096, M2, 512, 512, 512, M2, 0.015625f, 0);

  // --- fused attention (256 blocks, 1024 threads, pinned 128-VGPR budget) ---
  fused_attn<<<256, 1024, SMEMSZ, stream>>>(Qbf, Kbf, Vt, aobf, outA);

  // --- output projection + gate + final ---
  gemm_bf16<<<dim3(4, 32), 256, 0, stream>>>(aobf, Wobf, bo, nullptr, pj, nullptr,
                                             4096, 512, 512, 512, 512, 512, 1.0f, 0);
  cat_bf<<<4096, 256, 0, stream>>>(sfbf, pj, catbf);
  gemm_bf16<<<dim3(4, 32), 256, 0, stream>>>(catbf, Wagbf, bag, nullptr, gl, nullptr,
                                             4096, 512, 1024, 1024, 1024, 512, 1.0f, 0);
  final_kernel<<<4096, 256, 0, stream>>>(sf, pj, gl, nw, outF, gpart);
  gate_reduce<<<1, 256, 0, stream>>>(gpart, outG);
}